// Round 4
// baseline (352.236 us; speedup 1.0000x reference)
//
#include <hip/hip_runtime.h>
#include <math.h>

// Problem constants
#define BSZ 4
#define CCH 8192
#define HW  1024               // H*W = 32*32
#define DEMB 256
#define NPOS (BSZ*HW)          // 4096 spatial positions
#define QSIZE (BSZ*DEMB*HW)    // 1048576 floats (quantized)
#define KLOFF QSIZE            // kl scalar float offset in out
#define OHOFF (QSIZE+1)        // one_hot start (NOT 16B aligned)
#define OHSZ  ((size_t)BSZ*CCH*HW)  // 33554432

typedef float vf4 __attribute__((ext_vector_type(4)));
typedef float vf2 __attribute__((ext_vector_type(2)));

// Phase 1: block = (b, chunk of CPB channels, half of hw). 256 threads;
// thread t owns hw positions hw0+2t, hw0+2t+1 (vf2). Grid is 2x the old
// version (hw split) -> 16 waves/CU instead of 8, for latency hiding.
// x/g loads are CACHEABLE (re-read every iteration; L3 should retain them);
// the one_hot zeroing keeps write-once NT vf4 stores, re-tiled to cover this
// block's (CPB ch x 512 hw) region exactly once via the shifted-by-QSIZE
// trick (the b=0,q=0,h=0 flat=0 store also zeros the kl scalar at QSIZE).
template<int CPB>
__global__ __launch_bounds__(256) void vq_phase1(const float* __restrict__ x,
                                                 const float* __restrict__ g,
                                                 float* __restrict__ out,
                                                 float* __restrict__ ws) {
    constexpr int NCH = CCH / CPB;
    constexpr int P   = NPOS * NCH;
    constexpr int UN  = 16;
    constexpr int HHW = HW / 2;        // 512
    int bid = blockIdx.x;
    int h  = bid & 1;                  // hw half
    int qb = bid >> 1;
    int q = qb % NCH;
    int b = qb / NCH;
    int t = threadIdx.x;
    int c0 = q * CPB;
    int hw0 = h * HHW;
    size_t base = ((size_t)(b * CCH + c0)) * HW + hw0 + 2 * t;

    float best[2]; int bidx[2]; float s[2], sx[2];
#pragma unroll
    for (int j = 0; j < 2; j++) { best[j] = -INFINITY; bidx[j] = 0; s[j] = 0.f; sx[j] = 0.f; }

    const vf4 z4 = (vf4)(0.f);
    for (int cg = 0; cg < CPB / UN; cg++) {
        size_t a0 = base + (size_t)cg * UN * HW;
        vf2 xv[UN], gv[UN];
#pragma unroll
        for (int u = 0; u < UN; u++)
            xv[u] = *(const vf2*)(x + a0 + (size_t)u * HW);
#pragma unroll
        for (int u = 0; u < UN; u++)
            gv[u] = *(const vf2*)(g + a0 + (size_t)u * HW);

        // fused one_hot zeroing: this cg's 16 ch x 512 hw = 2048 vf4 stores,
        // 8 per thread, coalesced (flat = k*256+t), shifted by QSIZE.
        size_t zb = ((size_t)(b * CCH + c0 + cg * UN)) * HW + hw0;
#pragma unroll
        for (int k = 0; k < 8; k++) {
            int flat = k * 256 + t;
            int cl   = flat >> 7;          // 0..15 (channel within cg group)
            int off4 = (flat & 127) * 4;   // 0..508
            __builtin_nontemporal_store(z4, (vf4*)(out + QSIZE + zb + (size_t)cl * HW + off4));
        }

#pragma unroll
        for (int u = 0; u < UN; u++) {
            int cc = c0 + cg * UN + u;
#pragma unroll
            for (int j = 0; j < 2; j++) {
                float xa = xv[u][j];
                float z = xa + gv[u][j];
                if (z > best[j]) { best[j] = z; bidx[j] = cc; }
                s[j]  += __expf(xa);
                sx[j] += xa;
            }
        }
    }

    // single element not covered by the shifted tiling: one_hot[last]
    if (b == BSZ - 1 && q == NCH - 1 && h == 1 && t == 255)
        out[QSIZE + OHSZ] = 0.f;

    // partials laid out [q][pos] for coalesced phase-2 reads (8B stores)
    int o = q * NPOS + b * HW + hw0 + 2 * t;
    float* wbest = ws;
    int*   widx  = (int*)(ws + (size_t)P);
    float* wsum  = ws + 2 * (size_t)P;
    float* wsx   = ws + 3 * (size_t)P;
    *(float2*)(wbest + o) = make_float2(best[0], best[1]);
    *(int2*)  (widx  + o) = make_int2(bidx[0], bidx[1]);
    *(float2*)(wsum  + o) = make_float2(s[0], s[1]);
    *(float2*)(wsx   + o) = make_float2(sx[0], sx[1]);
}

// Phase 2 (fused finalize): grid NPOS/16 blocks x 256 threads.
// (a) merge NCH chunk-partials per position (thread = pl 0..15 x qg 0..15,
//     LDS merge), (b) write one_hot 1.0s + KL atomic, (c) load the 16
//     selected emb rows coalesced into LDS, transpose, and write the
//     quantized tile with per-thread 64B float4 runs.
template<int CPB>
__global__ __launch_bounds__(256) void vq_phase2(const float* __restrict__ emb,
                                                 float* __restrict__ out,
                                                 float* __restrict__ ws) {
    constexpr int NCH = CCH / CPB;
    constexpr int P   = NPOS * NCH;
    constexpr int QPT = NCH / 16;
    constexpr int TP  = 272;           // tile pitch (256+16)
    const float* wbest = ws;
    const int*   widx  = (const int*)(ws + (size_t)P);
    const float* wsum  = ws + 2 * (size_t)P;
    const float* wsx   = ws + 3 * (size_t)P;

    int tid = threadIdx.x;
    int pl = tid & 15;
    int qg = tid >> 4;
    int pos0 = blockIdx.x * 16;
    int pos = pos0 + pl;

    float fb = -INFINITY; int fi = 0;
    float fs = 0.f, fsx = 0.f;
    for (int i = 0; i < QPT; i++) {
        int q = qg * QPT + i;
        int o = q * NPOS + pos;
        float v = wbest[o]; int ci = widx[o];
        if (v > fb || (v == fb && ci < fi)) { fb = v; fi = ci; }
        fs  += wsum[o];
        fsx += wsx[o];
    }

    __shared__ float l_b [16][17];
    __shared__ int   l_i [16][17];
    __shared__ float l_s [16][17];
    __shared__ float l_sx[16][17];
    __shared__ float tsum[16];
    __shared__ int   smi[16];
    __shared__ float tile[16 * TP];
    l_b [qg][pl] = fb;
    l_i [qg][pl] = fi;
    l_s [qg][pl] = fs;
    l_sx[qg][pl] = fsx;
    __syncthreads();

    if (tid < 16) {
        int p = tid;
        float mb = l_b[0][p]; int mi = l_i[0][p];
        float ms = l_s[0][p], msx = l_sx[0][p];
        for (int qq = 1; qq < 16; qq++) {
            float v = l_b[qq][p]; int ci = l_i[qq][p];
            if (v > mb || (v == mb && ci < mi)) { mb = v; mi = ci; }
            ms  += l_s[qq][p];
            msx += l_sx[qq][p];
        }
        int mypos = pos0 + p;
        smi[p] = mi;
        int bb = mypos >> 10;
        int hw = mypos & (HW - 1);
        out[OHOFF + ((size_t)(bb * CCH + mi)) * HW + hw] = 1.0f;

        const float logt = -9.0109131783f;  // log(1/8192)
        tsum[p] = logt + __logf(ms) - msx * (1.0f / (float)CCH);
    }
    __syncthreads();
    if (tid == 0) {
        float tt = 0.f;
        for (int p = 0; p < 16; p++) tt += tsum[p];
        atomicAdd(out + KLOFF, (0.25f / (float)BSZ) * tt);
    }

    // (c) gather emb rows -> LDS (coalesced float4 loads, 4 rows per pass)
    int rr = tid >> 6;          // 0..3
    int c4 = (tid & 63) * 4;    // 0..252
#pragma unroll
    for (int rep = 0; rep < 4; rep++) {
        int r = rep * 4 + rr;
        float4 v = *(const float4*)(emb + (size_t)smi[r] * DEMB + c4);
        *(float4*)(tile + r * TP + c4) = v;
    }
    __syncthreads();

    // write quantized: thread d=tid owns a 64B run (16 hw) per 4-row group
    int b = pos0 >> 10;
    int hw0 = pos0 & (HW - 1);
    int d = tid;
    size_t obase = (((size_t)(b * DEMB + d)) << 10) + hw0;
#pragma unroll
    for (int k = 0; k < 4; k++) {
        float4 v;
        v.x = tile[(4 * k + 0) * TP + d];
        v.y = tile[(4 * k + 1) * TP + d];
        v.z = tile[(4 * k + 2) * TP + d];
        v.w = tile[(4 * k + 3) * TP + d];
        *(float4*)(out + obase + 4 * k) = v;
    }
}

template<int CPB>
static void launch_all(const float* x, const float* emb, const float* g,
                       float* out, float* ws, hipStream_t stream) {
    constexpr int NCH = CCH / CPB;
    vq_phase1<CPB><<<dim3(BSZ * NCH * 2), dim3(256), 0, stream>>>(x, g, out, ws);
    vq_phase2<CPB><<<dim3(NPOS / 16), dim3(256), 0, stream>>>(emb, out, ws);
}

extern "C" void kernel_launch(void* const* d_in, const int* in_sizes, int n_in,
                              void* d_out, int out_size, void* d_ws, size_t ws_size,
                              hipStream_t stream) {
    (void)in_sizes; (void)n_in; (void)out_size;
    const float* x   = (const float*)d_in[0];
    const float* emb = (const float*)d_in[1];
    const float* g   = (const float*)d_in[2];
    float* out = (float*)d_out;
    float* ws  = (float*)d_ws;

    // ws bytes needed: CPB=32 -> 16*(4096*256) ~= 16.8MB; CPB=64 ~= 8.4MB
    if (ws_size >= (size_t)16 * ((size_t)NPOS * (CCH / 32))) {
        launch_all<32>(x, emb, g, out, ws, stream);   // 2048 blocks
    } else {
        launch_all<64>(x, emb, g, out, ws, stream);   // 1024 blocks
    }
}